// Round 4
// baseline (288.647 us; speedup 1.0000x reference)
//
#include <hip/hip_runtime.h>

typedef short bf16x8 __attribute__((ext_vector_type(8)));
typedef float f32x4 __attribute__((ext_vector_type(4)));

#define BB 4
#define CC 64
#define HH 128
#define WW 128
#define KS 21
#define PAD 10

// padded f2 dims for the bf16 staging arrays
#define RR 148          // rows: rr = r+10, r in [-10,137]
#define VV 160          // cols: v' = w+dj in [0,148), padded to 160 so tile jj=9 is safe

#define A_ELEMS ((size_t)BB * HH * WW * CC)          // 4,194,304
#define B_ELEMS ((size_t)BB * RR * VV * CC)          // 6,062,080
#define WS_NEED ((2 * A_ELEMS + 2 * B_ELEMS) * 2)    // 41,025,536 bytes

__device__ inline ushort f2bf(float x) {             // fp32 -> bf16 RNE
    uint u = __float_as_uint(x);
    return (ushort)((u + 0x7FFFu + ((u >> 16) & 1u)) >> 16);
}
__device__ inline float bf2f(ushort h) { return __uint_as_float(((uint)h) << 16); }

// ---------- pre-pass: f1 [b][c][h][w] -> Ah/Al [b][h][w][c] (bf16 hi/lo) ----------
__global__ __launch_bounds__(256) void prep_a(const float* __restrict__ f1,
                                              ushort* __restrict__ Ah,
                                              ushort* __restrict__ Al) {
    const int idx = blockIdx.x * 256 + threadIdx.x;   // b*16384 + h*128 + w
    const int b = idx >> 14, hw = idx & 16383;
    const float* src = f1 + (size_t)b * (CC * HH * WW) + hw;
    ushort* dh = Ah + (size_t)idx * CC;
    ushort* dl = Al + (size_t)idx * CC;
#pragma unroll
    for (int k8 = 0; k8 < 8; ++k8) {
        bf16x8 vh, vl;
#pragma unroll
        for (int j = 0; j < 8; ++j) {
            float x = src[(size_t)(k8 * 8 + j) * (HH * WW)];
            ushort h16 = f2bf(x);
            vh[j] = (short)h16;
            vl[j] = (short)f2bf(x - bf2f(h16));
        }
        *(bf16x8*)(dh + k8 * 8) = vh;
        *(bf16x8*)(dl + k8 * 8) = vl;
    }
}

// ---------- pre-pass: f2 -> Bh/Bl [b][rr=148][vv=160][c], zero-padded ----------
__global__ __launch_bounds__(256) void prep_b(const float* __restrict__ f2,
                                              ushort* __restrict__ Bh,
                                              ushort* __restrict__ Bl) {
    const int idx = blockIdx.x * 256 + threadIdx.x;   // (b*RR+rr)*VV + vv
    const int vv = idx % VV;
    const int t  = idx / VV;
    const int rr = t % RR;
    const int b  = t / RR;
    const int r = rr - PAD, wc = vv - PAD;
    const bool ok = ((unsigned)r < HH) && ((unsigned)wc < WW);
    const float* src = f2 + ((size_t)(b * CC) * HH + (ok ? r : 0)) * WW + (ok ? wc : 0);
    ushort* dh = Bh + (size_t)idx * CC;
    ushort* dl = Bl + (size_t)idx * CC;
#pragma unroll
    for (int k8 = 0; k8 < 8; ++k8) {
        bf16x8 vh, vl;
#pragma unroll
        for (int j = 0; j < 8; ++j) {
            float x = ok ? src[(size_t)(k8 * 8 + j) * (HH * WW)] : 0.0f;
            ushort h16 = f2bf(x);
            vh[j] = (short)h16;
            vl[j] = (short)f2bf(x - bf2f(h16));
        }
        *(bf16x8*)(dh + k8 * 8) = vh;
        *(bf16x8*)(dl + k8 * 8) = vl;
    }
}

// ---------- main: banded GEMM via mfma_f32_16x16x32_bf16, 3-pass split ----------
// wave = (b, h, di, half). A-frags (4 w-tiles x 2 k-chunks x hi/lo) held in regs;
// jj-sweep loads B-frags once, reuses across <=3 w-tiles. No LDS, no barriers.
__global__ __launch_bounds__(256) void corr_mfma(const ushort* __restrict__ Ah,
                                                 const ushort* __restrict__ Al,
                                                 const ushort* __restrict__ Bh,
                                                 const ushort* __restrict__ Bl,
                                                 float* __restrict__ out) {
    const int lane = threadIdx.x & 63;
    // 5376 blocks = 8 XCD * 672; make consecutive-on-XCD blocks cover contiguous work
    const int blk = blockIdx.x;
    const int e = (blk & 7) * 672 + (blk >> 3);
    const int wid = e * 4 + (threadIdx.x >> 6);       // 0..21503
    const int grp = wid / 672;                        // (b, h-chunk16): 0..31
    const int wi  = wid % 672;
    const int b = grp >> 3, hc = grp & 7;
    const int half = wi & 1;
    const int t2 = wi >> 1;
    const int di  = t2 % 21;
    const int h   = hc * 16 + t2 / 21;

    const int i0 = half * 4;
    const int n  = lane & 15;          // also m-index for A loads
    const int kq = lane >> 4;          // k-quad 0..3

    // A fragments: A[m][k] with m=lane&15, k=kq*8+j  (c = q*32 + kq*8 + j)
    const size_t abase = (((size_t)(b * HH + h)) * WW + (i0 * 16 + n)) * CC + kq * 8;
    bf16x8 aH[4][2], aL[4][2];
#pragma unroll
    for (int ii = 0; ii < 4; ++ii)
#pragma unroll
        for (int q = 0; q < 2; ++q) {
            const size_t off = abase + (size_t)ii * (16 * CC) + q * 32;
            aH[ii][q] = *(const bf16x8*)(Ah + off);
            aL[ii][q] = *(const bf16x8*)(Al + off);
        }

    const int rr = h + di;             // in [0,148) always
    const size_t bbase = (((size_t)(b * RR + rr)) * VV + n) * CC + kq * 8;
    const size_t obase = ((size_t)b * (KS * KS) + (size_t)di * KS) * (HH * WW) + (size_t)h * WW;
    const float inv = 1.0f / (float)CC;

#pragma unroll
    for (int jt = 0; jt < 6; ++jt) {
        const int jj = i0 + jt;
        bf16x8 bH[2], bL[2];
#pragma unroll
        for (int q = 0; q < 2; ++q) {
            const size_t off = bbase + (size_t)jj * (16 * CC) + q * 32;
            bH[q] = *(const bf16x8*)(Bh + off);
            bL[q] = *(const bf16x8*)(Bl + off);
        }
        const int ilo = (jt < 2) ? 0 : jt - 2;
        const int ihi = (jt < 3) ? jt : 3;
#pragma unroll
        for (int ir = 0; ir < 4; ++ir) {
            if (ir < ilo || ir > ihi) continue;   // folds at compile time
            f32x4 acc = {0.f, 0.f, 0.f, 0.f};
            acc = __builtin_amdgcn_mfma_f32_16x16x32_bf16(aH[ir][0], bH[0], acc, 0, 0, 0);
            acc = __builtin_amdgcn_mfma_f32_16x16x32_bf16(aH[ir][1], bH[1], acc, 0, 0, 0);
            acc = __builtin_amdgcn_mfma_f32_16x16x32_bf16(aL[ir][0], bH[0], acc, 0, 0, 0);
            acc = __builtin_amdgcn_mfma_f32_16x16x32_bf16(aL[ir][1], bH[1], acc, 0, 0, 0);
            acc = __builtin_amdgcn_mfma_f32_16x16x32_bf16(aH[ir][0], bL[0], acc, 0, 0, 0);
            acc = __builtin_amdgcn_mfma_f32_16x16x32_bf16(aH[ir][1], bL[1], acc, 0, 0, 0);
            const int i = i0 + ir;
#pragma unroll
            for (int reg = 0; reg < 4; ++reg) {
                const int mm = kq * 4 + reg;            // C/D: row=(lane>>4)*4+reg
                const int w  = i * 16 + mm;
                const int dj = (jj - i) * 16 + n - mm;  // v' - w
                if (dj >= 0 && dj < KS)
                    out[obase + (size_t)dj * (HH * WW) + w] = acc[reg] * inv;
            }
        }
    }
}

// ---------- fallback (R1 kernel, known-good 130us) if ws is too small ----------
__global__ __launch_bounds__(256) void corr_fallback(
    const float* __restrict__ feat1, const float* __restrict__ feat2,
    float* __restrict__ out) {
    const int tid = threadIdx.x;
    int bi = blockIdx.x;
    const int di = bi % KS;  bi /= KS;
    const int h8 = bi % (HH / 8);
    const int b  = bi / (HH / 8);
    const int h  = h8 * 8 + (tid >> 5);
    const int w0 = (tid & 31) << 2;
    const int r = h + di - PAD;
    float acc[4][KS];
#pragma unroll
    for (int p = 0; p < 4; ++p)
#pragma unroll
        for (int d = 0; d < KS; ++d) acc[p][d] = 0.0f;
    if (r >= 0 && r < HH) {
        const float* f1p = feat1 + ((size_t)(b * CC) * HH + h) * WW + w0;
        const float* f2p = feat2 + ((size_t)(b * CC) * HH + r) * WW;
        for (int c = 0; c < CC; ++c) {
            const float4 a = *(const float4*)(f1p + (size_t)c * (HH * WW));
            float win[28];
#pragma unroll
            for (int j = 0; j < 7; ++j) {
                const int off = w0 - 12 + 4 * j;
                float4 v = make_float4(0.f, 0.f, 0.f, 0.f);
                if (off >= 0 && off < WW)
                    v = *(const float4*)(f2p + (size_t)c * (HH * WW) + off);
                win[4*j] = v.x; win[4*j+1] = v.y; win[4*j+2] = v.z; win[4*j+3] = v.w;
            }
#pragma unroll
            for (int d = 0; d < KS; ++d) {
                acc[0][d] += a.x * win[d + 2];
                acc[1][d] += a.y * win[d + 3];
                acc[2][d] += a.z * win[d + 4];
                acc[3][d] += a.w * win[d + 5];
            }
        }
    }
    const float scale = 1.0f / (float)CC;
    float* op = out + (((size_t)b * (KS * KS) + (size_t)di * KS) * HH + h) * WW + w0;
#pragma unroll
    for (int d = 0; d < KS; ++d) {
        float4 v = make_float4(acc[0][d]*scale, acc[1][d]*scale, acc[2][d]*scale, acc[3][d]*scale);
        *(float4*)(op + (size_t)d * (HH * WW)) = v;
    }
}

extern "C" void kernel_launch(void* const* d_in, const int* in_sizes, int n_in,
                              void* d_out, int out_size, void* d_ws, size_t ws_size,
                              hipStream_t stream) {
    const float* feat1 = (const float*)d_in[0];
    const float* feat2 = (const float*)d_in[1];
    float* out = (float*)d_out;

    if (ws_size < WS_NEED) {
        corr_fallback<<<BB * (HH / 8) * KS, 256, 0, stream>>>(feat1, feat2, out);
        return;
    }

    ushort* Ah = (ushort*)d_ws;
    ushort* Al = Ah + A_ELEMS;
    ushort* Bh = Al + A_ELEMS;
    ushort* Bl = Bh + B_ELEMS;

    prep_a<<<(BB * HH * WW) / 256, 256, 0, stream>>>(feat1, Ah, Al);
    prep_b<<<(BB * RR * VV) / 256, 256, 0, stream>>>(feat2, Bh, Bl);
    corr_mfma<<<5376, 256, 0, stream>>>(Ah, Al, Bh, Bl, out);
}